// Round 9
// baseline (253.314 us; speedup 1.0000x reference)
//
#include <hip/hip_runtime.h>
#include <math.h>

#define ALPHA 1.57f
#define BN_EPS 1e-5f

typedef __attribute__((ext_vector_type(8))) short short8v;
typedef __attribute__((ext_vector_type(4))) float f32x4;
typedef unsigned int uint32;
typedef unsigned short u16;

__device__ __forceinline__ u16 f2bf_rne(float f) {
    uint32 u = __float_as_uint(f);
    u += 0x7FFFu + ((u >> 16) & 1u);
    return (u16)(u >> 16);
}
__device__ __forceinline__ float bf2f(u16 h) {
    return __uint_as_float(((uint32)h) << 16);
}

// ---------------- Prep: split-bf16 weight fragments (once per call) ----------------
__global__ __launch_bounds__(256)
void prep_kernel(const float* __restrict__ w2, const float* __restrict__ w3,
                 u16* __restrict__ w2hi, u16* __restrict__ w2lo,
                 u16* __restrict__ w3hi, u16* __restrict__ w3lo)
{
    int t = blockIdx.x*256 + threadIdx.x;
    if (t < 5120) {
        int j = t & 7, col = (t>>3)&15, ct = (t>>7)&1, lg = (t>>8)&3, g = t>>10;
        int k = 32*g + 8*lg + j;
        int tap = k >> 4, ci = k & 15;
        float v = (tap < 9) ? w2[(ct*16+col)*144 + ci*9 + tap] : 0.f;
        u16 hi = f2bf_rne(v);
        w2hi[t] = hi;
        w2lo[t] = f2bf_rne(v - bf2f(hi));
    }
    if (t < 18432) {
        int j = t & 7, col = (t>>3)&15, ct = (t>>7)&3, lg = (t>>9)&3, g = t>>11;
        int ci = 8*lg + j;                 // tap = g
        float v = w3[(ct*16+col)*288 + ci*9 + g];
        u16 hi = f2bf_rne(v);
        w3hi[t] = hi;
        w3lo[t] = f2bf_rne(v - bf2f(hi));
    }
}

// ---------------- Stage 1: conv1(3->16) + BN + ReLU + pool2 ----------------
// x (1024,3,64,64) -> g1 (1024,16,32,32)
// v4: 512 thr, 8 waves x 2 co; per thread a 2x2 pooled tile (6x6 patch) per step,
// 2 steps. Rows stride 68 so patch rows are 16B-aligned -> b128+b64 reads.
__global__ __launch_bounds__(512)
void stage1_kernel(const float* __restrict__ x,
                   const float* __restrict__ w,    // (16,3,3,3)
                   const float* __restrict__ cb,
                   const float* __restrict__ bg,
                   const float* __restrict__ bb,
                   const float* __restrict__ bm,
                   const float* __restrict__ bv,
                   float* __restrict__ g1)
{
    __shared__ alignas(16) float simg[3*34*68];   // ci x 34 rows x 68 cols (data cols 1..65)
    __shared__ float sscale[16];
    __shared__ float sshift[16];
    const int im = blockIdx.x >> 1;
    const int h  = blockIdx.x & 1;    // half: pooled rows 16h..16h+15
    const int t  = threadIdx.x;

    // zero pad columns 0 (true -1) and 65 (true 64)
    if (t < 204) {                    // 3 ci * 34 rows * 2 cols
        int ci = t / 68;
        int r2 = t - ci*68;
        int ry = r2 >> 1;
        int col = (r2 & 1) ? 65 : 0;
        simg[ci*2312 + ry*68 + col] = 0.f;
    }
    if (t < 16) {
        float inv = bg[t] * rsqrtf(bv[t] + BN_EPS);
        sscale[t] = inv;
        sshift[t] = cb[t]*inv + bb[t] - bm[t]*inv;
    }

    // stage true rows 32h-1 .. 32h+32 (34 rows); OOB rows zeroed
    const float* xin = x + (size_t)im*12288;
    for (int i4 = t; i4 < 1632; i4 += 512) {   // 3*34*64/4
        int e   = i4 * 4;
        int ci  = e / 2176;
        int rem = e - ci*2176;
        int ry  = rem >> 6;
        int cx  = rem & 63;
        int g   = 32*h - 1 + ry;
        float4 vv = make_float4(0.f,0.f,0.f,0.f);
        if (g >= 0 && g < 64)
            vv = *reinterpret_cast<const float4*>(&xin[ci*4096 + g*64 + cx]);
        float* dst = &simg[ci*2312 + ry*68 + cx + 1];
        dst[0]=vv.x; dst[1]=vv.y; dst[2]=vv.z; dst[3]=vv.w;
    }
    __syncthreads();

    const int wv   = __builtin_amdgcn_readfirstlane(t >> 6);  // 0..7
    const int lane = t & 63;
    const int co0  = wv*2, co1 = wv*2 + 1;
    const int tr   = lane >> 4;       // tile row within step (0..3)
    const int tc   = lane & 15;       // tile col (0..15)

    // hoist all 54 weights (wave-uniform -> SGPRs)
    float W0[27], W1[27];
    #pragma unroll
    for (int i = 0; i < 27; ++i) {
        W0[i] = w[co0*27 + i];
        W1[i] = w[co1*27 + i];
    }
    const float sc0 = sscale[co0], sh0 = sshift[co0];
    const float sc1 = sscale[co1], sh1 = sshift[co1];

    #pragma unroll 1
    for (int step = 0; step < 2; ++step) {
        const int trr = step*4 + tr;          // tile row 0..7
        const int r0  = 4*trr;                // staged row origin (prepool rows r0..r0+3)
        float acc0[4][4], acc1[4][4];
        #pragma unroll
        for (int i = 0; i < 4; ++i)
            #pragma unroll
            for (int j = 0; j < 4; ++j) { acc0[i][j]=0.f; acc1[i][j]=0.f; }

        #pragma unroll
        for (int ci = 0; ci < 3; ++ci) {
            float p[6][6];
            const int base = ci*2312 + r0*68 + 4*tc;   // dword idx, %4==0 -> 16B aligned
            #pragma unroll
            for (int i = 0; i < 6; ++i) {
                float4 a = *reinterpret_cast<const float4*>(&simg[base + i*68]);
                float2 b = *reinterpret_cast<const float2*>(&simg[base + i*68 + 4]);
                p[i][0]=a.x; p[i][1]=a.y; p[i][2]=a.z; p[i][3]=a.w;
                p[i][4]=b.x; p[i][5]=b.y;
            }
            #pragma unroll
            for (int ky = 0; ky < 3; ++ky)
                #pragma unroll
                for (int kx = 0; kx < 3; ++kx) {
                    float w0 = W0[ci*9 + ky*3 + kx];
                    float w1 = W1[ci*9 + ky*3 + kx];
                    #pragma unroll
                    for (int ir = 0; ir < 4; ++ir)
                        #pragma unroll
                        for (int jc = 0; jc < 4; ++jc) {
                            float e = p[ir+ky][jc+kx];
                            acc0[ir][jc] = fmaf(w0, e, acc0[ir][jc]);
                            acc1[ir][jc] = fmaf(w1, e, acc1[ir][jc]);
                        }
                }
        }

        // epilogue: BN -> pool 2x2 -> ReLU -> float2 stores
        const int py0 = 2*trr;               // pooled row origin (local 0..15)
        const int px0 = 2*tc;                // pooled col origin (0..30 even)
        #pragma unroll
        for (int dy = 0; dy < 2; ++dy) {
            float2 o0, o1;
            {
                float v00 = fmaf(acc0[2*dy  ][0], sc0, sh0);
                float v01 = fmaf(acc0[2*dy  ][1], sc0, sh0);
                float v10 = fmaf(acc0[2*dy+1][0], sc0, sh0);
                float v11 = fmaf(acc0[2*dy+1][1], sc0, sh0);
                o0.x = fmaxf(fmaxf(fmaxf(v00,v01), fmaxf(v10,v11)), 0.f);
                v00 = fmaf(acc0[2*dy  ][2], sc0, sh0);
                v01 = fmaf(acc0[2*dy  ][3], sc0, sh0);
                v10 = fmaf(acc0[2*dy+1][2], sc0, sh0);
                v11 = fmaf(acc0[2*dy+1][3], sc0, sh0);
                o0.y = fmaxf(fmaxf(fmaxf(v00,v01), fmaxf(v10,v11)), 0.f);
                v00 = fmaf(acc1[2*dy  ][0], sc1, sh1);
                v01 = fmaf(acc1[2*dy  ][1], sc1, sh1);
                v10 = fmaf(acc1[2*dy+1][0], sc1, sh1);
                v11 = fmaf(acc1[2*dy+1][1], sc1, sh1);
                o1.x = fmaxf(fmaxf(fmaxf(v00,v01), fmaxf(v10,v11)), 0.f);
                v00 = fmaf(acc1[2*dy  ][2], sc1, sh1);
                v01 = fmaf(acc1[2*dy  ][3], sc1, sh1);
                v10 = fmaf(acc1[2*dy+1][2], sc1, sh1);
                v11 = fmaf(acc1[2*dy+1][3], sc1, sh1);
                o1.y = fmaxf(fmaxf(fmaxf(v00,v01), fmaxf(v10,v11)), 0.f);
            }
            int row = (16*h + py0 + dy)*32 + px0;
            *reinterpret_cast<float2*>(&g1[(((size_t)im*16 + co0) << 10) + row]) = o0;
            *reinterpret_cast<float2*>(&g1[(((size_t)im*16 + co1) << 10) + row]) = o1;
        }
    }
}

// ---------------- Stage 2: conv2(16->32) MFMA, channel-last hi/lo LDS ----------------
__global__ __launch_bounds__(512)
void stage2_kernel(const float* __restrict__ g1,
                   const u16* __restrict__ w2hi, const u16* __restrict__ w2lo,
                   const float* __restrict__ cb,
                   const float* __restrict__ bg,
                   const float* __restrict__ bb,
                   const float* __restrict__ bm,
                   const float* __restrict__ bv,
                   float* __restrict__ g2)
{
    __shared__ alignas(16) u16 imgHi[18*34*24];
    __shared__ alignas(16) u16 imgLo[18*34*24];
    __shared__ float sscale[32];
    __shared__ float sshift[32];
    const int im = blockIdx.x >> 1;
    const int h  = blockIdx.x & 1;
    const int t  = threadIdx.x;

    {
        uint32* p0 = (uint32*)imgHi;
        uint32* p1 = (uint32*)imgLo;
        for (int i = t; i < 7344; i += 512) { p0[i] = 0u; p1[i] = 0u; }
    }
    if (t < 32) {
        float inv = bg[t] * rsqrtf(bv[t] + BN_EPS);
        sscale[t] = inv;
        sshift[t] = cb[t]*inv + bb[t] - bm[t]*inv;
    }
    __syncthreads();

    const float* gin = g1 + (size_t)im*16384;
    for (int i4 = t; i4 < 2304; i4 += 512) {
        int ci  = ((i4 >> 4)*57) >> 9;
        int rem = i4 - ci*144;
        int r   = rem >> 3;
        int x4  = rem & 7;
        int gy  = 16*h - 1 + r;
        float4 vv = make_float4(0.f,0.f,0.f,0.f);
        if (gy >= 0 && gy < 32)
            vv = *reinterpret_cast<const float4*>(&gin[ci*1024 + gy*32 + 4*x4]);
        int base = (r*34 + 4*x4 + 1)*24 + ci;
        float fv[4] = {vv.x, vv.y, vv.z, vv.w};
        #pragma unroll
        for (int d = 0; d < 4; ++d) {
            u16 hi = f2bf_rne(fv[d]);
            imgHi[base + d*24] = hi;
            imgLo[base + d*24] = f2bf_rne(fv[d] - bf2f(hi));
        }
    }
    __syncthreads();

    const int wv   = __builtin_amdgcn_readfirstlane(t >> 6);
    const int lane = t & 63;
    const int lg   = lane >> 4;
    const int col  = lane & 15;

    f32x4 acc[2][2][2];
    #pragma unroll
    for (int a0 = 0; a0 < 2; ++a0)
        #pragma unroll
        for (int a1 = 0; a1 < 2; ++a1)
            #pragma unroll
            for (int a2 = 0; a2 < 2; ++a2)
                acc[a0][a1][a2] = (f32x4){0.f,0.f,0.f,0.f};

    const short8v* w2h8 = (const short8v*)w2hi;
    const short8v* w2l8 = (const short8v*)w2lo;

    #pragma unroll
    for (int g = 0; g < 5; ++g) {
        short8v ah[2], al[2];
        #pragma unroll
        for (int ct = 0; ct < 2; ++ct) {
            int fidx = ((g*4 + lg)*2 + ct)*16 + col;
            ah[ct] = w2h8[fidx];
            al[ct] = w2l8[fidx];
        }
        int tap = 2*g + (lg >> 1);
        tap = (tap > 8) ? 8 : tap;
        int ky = (tap*11) >> 5;
        int kx = tap - 3*ky;
        int ci0 = (lg & 1)*8;
        #pragma unroll
        for (int ntoy = 0; ntoy < 2; ++ntoy) {
            #pragma unroll
            for (int oxh = 0; oxh < 2; ++oxh) {
                int addr = ((2*wv + ntoy + ky)*34 + oxh*16 + col + kx)*24 + ci0;
                short8v bh = *(const short8v*)&imgHi[addr];
                short8v bl = *(const short8v*)&imgLo[addr];
                #pragma unroll
                for (int ct = 0; ct < 2; ++ct) {
                    acc[ct][ntoy][oxh] = __builtin_amdgcn_mfma_f32_16x16x32_bf16(
                        ah[ct], bh, acc[ct][ntoy][oxh], 0, 0, 0);
                    acc[ct][ntoy][oxh] = __builtin_amdgcn_mfma_f32_16x16x32_bf16(
                        ah[ct], bl, acc[ct][ntoy][oxh], 0, 0, 0);
                    acc[ct][ntoy][oxh] = __builtin_amdgcn_mfma_f32_16x16x32_bf16(
                        al[ct], bh, acc[ct][ntoy][oxh], 0, 0, 0);
                }
            }
        }
    }

    #pragma unroll
    for (int ct = 0; ct < 2; ++ct) {
        #pragma unroll
        for (int oxh = 0; oxh < 2; ++oxh) {
            #pragma unroll
            for (int r = 0; r < 4; ++r) {
                int co = ct*16 + 4*lg + r;
                float sc = sscale[co], sh = sshift[co];
                float v0 = fmaf(acc[ct][0][oxh][r], sc, sh);
                float v1 = fmaf(acc[ct][1][oxh][r], sc, sh);
                float m = fmaxf(v0, v1);
                float o = __shfl_xor(m, 1);
                m = fmaxf(fmaxf(m, o), 0.f);
                if (!(col & 1)) {
                    int px = oxh*8 + (col >> 1);
                    g2[(((size_t)im*32 + co) << 8) + (8*h + wv)*16 + px] = m;
                }
            }
        }
    }
}

// ------- Stage 3: conv3(32->64) MFMA + BN/ReLU/pool + proj + quantum + cls -------
__global__ __launch_bounds__(512)
void stage3_kernel(const float* __restrict__ g2,
                   const u16* __restrict__ w3hi, const u16* __restrict__ w3lo,
                   const float* __restrict__ cb,
                   const float* __restrict__ bg,
                   const float* __restrict__ bb,
                   const float* __restrict__ bm,
                   const float* __restrict__ bv,
                   const float* __restrict__ pw,
                   const float* __restrict__ pb,
                   const float* __restrict__ cw,
                   const float* __restrict__ cbias,
                   float* __restrict__ out)
{
    __shared__ alignas(16) u16 imgHi[18*18*40];
    __shared__ alignas(16) u16 imgLo[18*18*40];
    __shared__ float sscale[64];
    __shared__ float sshift[64];
    __shared__ float red[8][4];
    float* fbuf = (float*)imgHi;
    const int b = blockIdx.x;
    const int t = threadIdx.x;

    {
        uint32* p0 = (uint32*)imgHi;
        uint32* p1 = (uint32*)imgLo;
        for (int i = t; i < 6480; i += 512) { p0[i] = 0u; p1[i] = 0u; }
    }
    if (t < 64) {
        float inv = bg[t] * rsqrtf(bv[t] + BN_EPS);
        sscale[t] = inv;
        sshift[t] = cb[t]*inv + bb[t] - bm[t]*inv;
    }
    __syncthreads();

    const float* gin = g2 + (size_t)b*8192;
    #pragma unroll
    for (int k = 0; k < 4; ++k) {
        int i4 = t + k*512;
        int x4 = i4 & 3;
        int y  = (i4 >> 2) & 15;
        int ci = i4 >> 6;
        float4 vv = *reinterpret_cast<const float4*>(&gin[ci*256 + y*16 + 4*x4]);
        int base = ((y+1)*18 + 4*x4 + 1)*40 + ci;
        float fv[4] = {vv.x, vv.y, vv.z, vv.w};
        #pragma unroll
        for (int d = 0; d < 4; ++d) {
            u16 hi = f2bf_rne(fv[d]);
            imgHi[base + d*40] = hi;
            imgLo[base + d*40] = f2bf_rne(fv[d] - bf2f(hi));
        }
    }
    __syncthreads();

    const int wv   = __builtin_amdgcn_readfirstlane(t >> 6);
    const int lane = t & 63;
    const int lg   = lane >> 4;
    const int col  = lane & 15;

    f32x4 acc[4][2];
    #pragma unroll
    for (int a0 = 0; a0 < 4; ++a0) {
        acc[a0][0] = (f32x4){0.f,0.f,0.f,0.f};
        acc[a0][1] = (f32x4){0.f,0.f,0.f,0.f};
    }

    const short8v* w3h8 = (const short8v*)w3hi;
    const short8v* w3l8 = (const short8v*)w3lo;

    #pragma unroll
    for (int g = 0; g < 9; ++g) {
        short8v ah[4], al[4];
        #pragma unroll
        for (int ct = 0; ct < 4; ++ct) {
            int fidx = ((g*4 + lg)*4 + ct)*16 + col;
            ah[ct] = w3h8[fidx];
            al[ct] = w3l8[fidx];
        }
        int ky = (g*11) >> 5;
        int kx = g - 3*ky;
        int ci0 = 8*lg;
        #pragma unroll
        for (int ntoy = 0; ntoy < 2; ++ntoy) {
            int addr = ((2*wv + ntoy + ky)*18 + col + kx)*40 + ci0;
            short8v bh = *(const short8v*)&imgHi[addr];
            short8v bl = *(const short8v*)&imgLo[addr];
            #pragma unroll
            for (int ct = 0; ct < 4; ++ct) {
                acc[ct][ntoy] = __builtin_amdgcn_mfma_f32_16x16x32_bf16(
                    ah[ct], bh, acc[ct][ntoy], 0, 0, 0);
                acc[ct][ntoy] = __builtin_amdgcn_mfma_f32_16x16x32_bf16(
                    ah[ct], bl, acc[ct][ntoy], 0, 0, 0);
                acc[ct][ntoy] = __builtin_amdgcn_mfma_f32_16x16x32_bf16(
                    al[ct], bh, acc[ct][ntoy], 0, 0, 0);
            }
        }
    }
    __syncthreads();

    #pragma unroll
    for (int ct = 0; ct < 4; ++ct) {
        #pragma unroll
        for (int r = 0; r < 4; ++r) {
            int co = ct*16 + 4*lg + r;
            float sc = sscale[co], sh = sshift[co];
            float v0 = fmaf(acc[ct][0][r], sc, sh);
            float v1 = fmaf(acc[ct][1][r], sc, sh);
            float m = fmaxf(v0, v1);
            float o = __shfl_xor(m, 1);
            m = fmaxf(fmaxf(m, o), 0.f);
            if (!(col & 1))
                fbuf[co*64 + wv*8 + (col >> 1)] = m;
        }
    }
    __syncthreads();

    float z0=0.f, z1=0.f, z2=0.f, z3=0.f;
    #pragma unroll
    for (int k = 0; k < 8; ++k) {
        int j = k*512 + t;
        float fv = fbuf[j];
        z0 = fmaf(fv, pw[        j], z0);
        z1 = fmaf(fv, pw[ 4096 + j], z1);
        z2 = fmaf(fv, pw[ 8192 + j], z2);
        z3 = fmaf(fv, pw[12288 + j], z3);
    }
    #pragma unroll
    for (int off2 = 32; off2 > 0; off2 >>= 1) {
        z0 += __shfl_down(z0, off2);
        z1 += __shfl_down(z1, off2);
        z2 += __shfl_down(z2, off2);
        z3 += __shfl_down(z3, off2);
    }
    if (lane == 0) { red[wv][0]=z0; red[wv][1]=z1; red[wv][2]=z2; red[wv][3]=z3; }
    __syncthreads();

    if (t == 0) {
        float z[4];
        #pragma unroll
        for (int p2 = 0; p2 < 4; ++p2) {
            float s = pb[p2];
            #pragma unroll
            for (int r = 0; r < 8; ++r) s += red[r][p2];
            z[p2] = s;
        }
        float qc[4], qs[4];
        #pragma unroll
        for (int k = 0; k < 4; ++k) {
            float hh = 0.5f * ALPHA * z[k];
            qc[k] = cosf(hh);
            qs[k] = sinf(hh);
        }
        float st[16];
        #pragma unroll
        for (int j = 0; j < 16; ++j) {
            float v0 = ((j>>3)&1) ? qs[0] : qc[0];
            float v1 = ((j>>2)&1) ? qs[1] : qc[1];
            float v2 = ((j>>1)&1) ? qs[2] : qc[2];
            float v3 = ( j    &1) ? qs[3] : qc[3];
            st[j] = v0*v1*v2*v3;
        }
        const int csrc[4] = {0,1,2,3};
        const int ctgt[4] = {1,2,3,0};
        #pragma unroll
        for (int pp = 0; pp < 4; ++pp) {
            float tmp[16];
            #pragma unroll
            for (int idx = 0; idx < 16; ++idx) {
                int bit = (idx >> (3 - csrc[pp])) & 1;
                int src = bit ? (idx ^ (1 << (3 - ctgt[pp]))) : idx;
                tmp[idx] = st[src];
            }
            #pragma unroll
            for (int idx = 0; idx < 16; ++idx) st[idx] = tmp[idx];
        }
        float feat[10];
        #pragma unroll
        for (int f = 0; f < 10; ++f) feat[f] = 0.f;
        #pragma unroll
        for (int j = 0; j < 16; ++j) {
            float pr = st[j]*st[j];
            float s0 = ((j>>3)&1) ? -1.f : 1.f;
            float s1 = ((j>>2)&1) ? -1.f : 1.f;
            float s2 = ((j>>1)&1) ? -1.f : 1.f;
            float s3 = ( j    &1) ? -1.f : 1.f;
            feat[0] += s0*pr;       feat[1] += s1*pr;
            feat[2] += s2*pr;       feat[3] += s3*pr;
            feat[4] += s0*s1*pr;    feat[5] += s0*s2*pr;
            feat[6] += s0*s3*pr;    feat[7] += s1*s2*pr;
            feat[8] += s1*s3*pr;    feat[9] += s2*s3*pr;
        }
        #pragma unroll
        for (int o = 0; o < 10; ++o) {
            float a = cbias[o];
            #pragma unroll
            for (int f = 0; f < 10; ++f) a = fmaf(feat[f], cw[o*10+f], a);
            out[(size_t)b*10 + o] = a;
        }
    }
}

extern "C" void kernel_launch(void* const* d_in, const int* in_sizes, int n_in,
                              void* d_out, int out_size, void* d_ws, size_t ws_size,
                              hipStream_t stream)
{
    const float* x   = (const float*)d_in[0];
    const float* c1w = (const float*)d_in[1];
    const float* c1b = (const float*)d_in[2];
    const float* c2w = (const float*)d_in[3];
    const float* c2b = (const float*)d_in[4];
    const float* c3w = (const float*)d_in[5];
    const float* c3b = (const float*)d_in[6];
    const float* b1g = (const float*)d_in[7];
    const float* b1b = (const float*)d_in[8];
    const float* b1m = (const float*)d_in[9];
    const float* b1v = (const float*)d_in[10];
    const float* b2g = (const float*)d_in[11];
    const float* b2b = (const float*)d_in[12];
    const float* b2m = (const float*)d_in[13];
    const float* b2v = (const float*)d_in[14];
    const float* b3g = (const float*)d_in[15];
    const float* b3b = (const float*)d_in[16];
    const float* b3m = (const float*)d_in[17];
    const float* b3v = (const float*)d_in[18];
    const float* pw  = (const float*)d_in[19];
    const float* pb  = (const float*)d_in[20];
    const float* cw  = (const float*)d_in[21];
    const float* cbv = (const float*)d_in[22];

    char* wsb = (char*)d_ws;
    float* g1 = (float*)wsb;                               // 64 MB
    float* g2 = (float*)(wsb + 67108864);                  // 32 MB
    u16* w2hi = (u16*)(wsb + 100663296);                   // frag arrays (~92 KB)
    u16* w2lo = w2hi + 5120;
    u16* w3hi = w2lo + 5120;
    u16* w3lo = w3hi + 18432;
    float* out = (float*)d_out;

    prep_kernel  <<<  72, 256, 0, stream>>>(c2w, c3w, w2hi, w2lo, w3hi, w3lo);
    stage1_kernel<<<2048, 512, 0, stream>>>(x,  c1w, c1b, b1g, b1b, b1m, b1v, g1);
    stage2_kernel<<<2048, 512, 0, stream>>>(g1, w2hi, w2lo, c2b, b2g, b2b, b2m, b2v, g2);
    stage3_kernel<<<1024, 512, 0, stream>>>(g2, w3hi, w3lo, c3b, b3g, b3b, b3m, b3v,
                                            pw, pb, cw, cbv, out);
}

// Round 10
// 225.779 us; speedup vs baseline: 1.1220x; 1.1220x over previous
//
#include <hip/hip_runtime.h>
#include <math.h>

#define ALPHA 1.57f
#define BN_EPS 1e-5f

typedef __attribute__((ext_vector_type(8))) short short8v;
typedef __attribute__((ext_vector_type(4))) short short4v;
typedef __attribute__((ext_vector_type(4))) float f32x4;
typedef unsigned int uint32;
typedef unsigned short u16;

__device__ __forceinline__ u16 f2bf_rne(float f) {
    uint32 u = __float_as_uint(f);
    u += 0x7FFFu + ((u >> 16) & 1u);
    return (u16)(u >> 16);
}
__device__ __forceinline__ float bf2f(u16 h) {
    return __uint_as_float(((uint32)h) << 16);
}

// ---------------- Prep: split-bf16 weight fragments (once per call) ----------------
__global__ __launch_bounds__(256)
void prep_kernel(const float* __restrict__ w2, const float* __restrict__ w3,
                 u16* __restrict__ w2hi, u16* __restrict__ w2lo,
                 u16* __restrict__ w3hi, u16* __restrict__ w3lo)
{
    int t = blockIdx.x*256 + threadIdx.x;
    if (t < 5120) {
        int j = t & 7, col = (t>>3)&15, ct = (t>>7)&1, lg = (t>>8)&3, g = t>>10;
        int k = 32*g + 8*lg + j;
        int tap = k >> 4, ci = k & 15;
        float v = (tap < 9) ? w2[(ct*16+col)*144 + ci*9 + tap] : 0.f;
        u16 hi = f2bf_rne(v);
        w2hi[t] = hi;
        w2lo[t] = f2bf_rne(v - bf2f(hi));
    }
    if (t < 18432) {
        int j = t & 7, col = (t>>3)&15, ct = (t>>7)&3, lg = (t>>9)&3, g = t>>11;
        int ci = 8*lg + j;                 // tap = g
        float v = w3[(ct*16+col)*288 + ci*9 + g];
        u16 hi = f2bf_rne(v);
        w3hi[t] = hi;
        w3lo[t] = f2bf_rne(v - bf2f(hi));
    }
}

// ---------------- Stage 1: conv1(3->16) via MFMA implicit GEMM ----------------
// x (1024,3,64,64) -> g1 (1024,16,32,32).  2 blocks/image (half + halo), 512 thr.
// K = tap*4 + ci (ci-pad-4): chunk0 = taps0..7, chunk1 = tap8. Split-bf16 x3.
// LDS: imgHi/imgLo u16 [34 rows][66 cols][4 ci] -> every frag half = 1 ds_read_b64.
__global__ __launch_bounds__(512)
void stage1_kernel(const float* __restrict__ x,
                   const float* __restrict__ w,    // (16,3,3,3): co*27 + ci*9 + tap
                   const float* __restrict__ cb,
                   const float* __restrict__ bg,
                   const float* __restrict__ bb,
                   const float* __restrict__ bm,
                   const float* __restrict__ bv,
                   float* __restrict__ g1)
{
    __shared__ alignas(16) u16 imgHi[34*66*4];   // 8976 u16 = 17952 B
    __shared__ alignas(16) u16 imgLo[34*66*4];
    __shared__ float sscale[16];
    __shared__ float sshift[16];
    const int im = blockIdx.x >> 1;
    const int h  = blockIdx.x & 1;    // half: pooled rows 16h..16h+15
    const int t  = threadIdx.x;

    {   // zero both planes (pads + ci=3 plane must be 0)
        uint32* p0 = (uint32*)imgHi;
        uint32* p1 = (uint32*)imgLo;
        for (int i = t; i < 4488; i += 512) { p0[i] = 0u; p1[i] = 0u; }
    }
    if (t < 16) {
        float inv = bg[t] * rsqrtf(bv[t] + BN_EPS);
        sscale[t] = inv;
        sshift[t] = cb[t]*inv + bb[t] - bm[t]*inv;
    }
    __syncthreads();

    // stage true rows 32h-1 .. 32h+32 (34 rows) as split-bf16, channel-last
    const float* xin = x + (size_t)im*12288;
    for (int i4 = t; i4 < 1632; i4 += 512) {   // 3ci * 34r * 64c / 4
        int e   = i4 * 4;
        int ci  = e / 2176;
        int rem = e - ci*2176;
        int ry  = rem >> 6;
        int cx  = rem & 63;
        int gy  = 32*h - 1 + ry;
        float4 vv = make_float4(0.f,0.f,0.f,0.f);
        if (gy >= 0 && gy < 64)
            vv = *reinterpret_cast<const float4*>(&xin[ci*4096 + gy*64 + cx]);
        int base = (ry*66 + cx + 1)*4 + ci;
        float fv[4] = {vv.x, vv.y, vv.z, vv.w};
        #pragma unroll
        for (int d = 0; d < 4; ++d) {
            u16 hi = f2bf_rne(fv[d]);
            imgHi[base + d*4] = hi;
            imgLo[base + d*4] = f2bf_rne(fv[d] - bf2f(hi));
        }
    }
    __syncthreads();

    const int wv   = __builtin_amdgcn_readfirstlane(t >> 6);  // 0..7
    const int lane = t & 63;
    const int lg   = lane >> 4;
    const int col  = lane & 15;      // A-row (=co) and B-col (=position)

    // A fragments from global (L2-hot), built once per block.
    short8v ah0, al0, ah1, al1;
    #pragma unroll
    for (int j = 0; j < 8; ++j) {
        int ci  = j & 3;
        int tap = 2*lg + (j >> 2);          // chunk0: taps 0..7
        float v0 = (ci < 3) ? w[col*27 + ci*9 + tap] : 0.f;
        u16 hi = f2bf_rne(v0);
        ah0[j] = (short)hi;
        al0[j] = (short)f2bf_rne(v0 - bf2f(hi));
        int tap1 = 8 + 2*lg + (j >> 2);     // chunk1: only tap 8 real
        float v1 = (ci < 3 && tap1 < 9) ? w[col*27 + ci*9 + tap1] : 0.f;
        hi = f2bf_rne(v1);
        ah1[j] = (short)hi;
        al1[j] = (short)f2bf_rne(v1 - bf2f(hi));
    }

    // chunk0 tap pair offsets (u16 units); chunk1 = tap8 = (ky2,kx2)
    const int tA = 2*lg, tB = 2*lg + 1;
    const int offA = ((tA/3)*66 + (tA - 3*(tA/3)))*4;
    const int offB = ((tB/3)*66 + (tB - 3*(tB/3)))*4;
    const int offC = (2*66 + 2)*4;

    for (int q = 0; q < 2; ++q) {
        int py = 2*wv + q;                  // pooled row 0..15 (local)
        #pragma unroll
        for (int ct4 = 0; ct4 < 4; ++ct4) {
            int ox = ct4*16 + col;          // prepool col 0..63
            f32x4 acc[2];
            acc[0] = (f32x4){0.f,0.f,0.f,0.f};
            acc[1] = (f32x4){0.f,0.f,0.f,0.f};
            #pragma unroll
            for (int rr = 0; rr < 2; ++rr) {
                int r = 2*py + rr;          // prepool row 0..31
                int base = (r*66 + ox)*4;
                short8v bh0, bl0, bh1, bl1;
                *reinterpret_cast<short4v*>(&bh0) =
                    *reinterpret_cast<const short4v*>(&imgHi[base + offA]);
                *(reinterpret_cast<short4v*>(&bh0) + 1) =
                    *reinterpret_cast<const short4v*>(&imgHi[base + offB]);
                *reinterpret_cast<short4v*>(&bl0) =
                    *reinterpret_cast<const short4v*>(&imgLo[base + offA]);
                *(reinterpret_cast<short4v*>(&bl0) + 1) =
                    *reinterpret_cast<const short4v*>(&imgLo[base + offB]);
                *reinterpret_cast<short4v*>(&bh1) =
                    *reinterpret_cast<const short4v*>(&imgHi[base + offC]);
                *(reinterpret_cast<short4v*>(&bh1) + 1) = (short4v){0,0,0,0};
                *reinterpret_cast<short4v*>(&bl1) =
                    *reinterpret_cast<const short4v*>(&imgLo[base + offC]);
                *(reinterpret_cast<short4v*>(&bl1) + 1) = (short4v){0,0,0,0};

                acc[rr] = __builtin_amdgcn_mfma_f32_16x16x32_bf16(ah0, bh0, acc[rr], 0,0,0);
                acc[rr] = __builtin_amdgcn_mfma_f32_16x16x32_bf16(ah0, bl0, acc[rr], 0,0,0);
                acc[rr] = __builtin_amdgcn_mfma_f32_16x16x32_bf16(al0, bh0, acc[rr], 0,0,0);
                acc[rr] = __builtin_amdgcn_mfma_f32_16x16x32_bf16(ah1, bh1, acc[rr], 0,0,0);
                acc[rr] = __builtin_amdgcn_mfma_f32_16x16x32_bf16(ah1, bl1, acc[rr], 0,0,0);
                acc[rr] = __builtin_amdgcn_mfma_f32_16x16x32_bf16(al1, bh1, acc[rr], 0,0,0);
            }
            // epilogue: BN -> pool 2x2 -> ReLU -> store (even-col lanes)
            #pragma unroll
            for (int r2 = 0; r2 < 4; ++r2) {
                int co = 4*lg + r2;
                float sc = sscale[co], sh = sshift[co];
                float v0 = fmaf(acc[0][r2], sc, sh);
                float v1 = fmaf(acc[1][r2], sc, sh);
                float m = fmaxf(v0, v1);
                float o = __shfl_xor(m, 1);
                m = fmaxf(fmaxf(m, o), 0.f);
                if (!(col & 1)) {
                    int px = ox >> 1;       // pooled col 0..31
                    g1[(((size_t)im*16 + co) << 10) + (16*h + py)*32 + px] = m;
                }
            }
        }
    }
}

// ---------------- Stage 2: conv2(16->32) MFMA, channel-last hi/lo LDS ----------------
__global__ __launch_bounds__(512)
void stage2_kernel(const float* __restrict__ g1,
                   const u16* __restrict__ w2hi, const u16* __restrict__ w2lo,
                   const float* __restrict__ cb,
                   const float* __restrict__ bg,
                   const float* __restrict__ bb,
                   const float* __restrict__ bm,
                   const float* __restrict__ bv,
                   float* __restrict__ g2)
{
    __shared__ alignas(16) u16 imgHi[18*34*24];
    __shared__ alignas(16) u16 imgLo[18*34*24];
    __shared__ float sscale[32];
    __shared__ float sshift[32];
    const int im = blockIdx.x >> 1;
    const int h  = blockIdx.x & 1;
    const int t  = threadIdx.x;

    {
        uint32* p0 = (uint32*)imgHi;
        uint32* p1 = (uint32*)imgLo;
        for (int i = t; i < 7344; i += 512) { p0[i] = 0u; p1[i] = 0u; }
    }
    if (t < 32) {
        float inv = bg[t] * rsqrtf(bv[t] + BN_EPS);
        sscale[t] = inv;
        sshift[t] = cb[t]*inv + bb[t] - bm[t]*inv;
    }
    __syncthreads();

    const float* gin = g1 + (size_t)im*16384;
    for (int i4 = t; i4 < 2304; i4 += 512) {
        int ci  = ((i4 >> 4)*57) >> 9;
        int rem = i4 - ci*144;
        int r   = rem >> 3;
        int x4  = rem & 7;
        int gy  = 16*h - 1 + r;
        float4 vv = make_float4(0.f,0.f,0.f,0.f);
        if (gy >= 0 && gy < 32)
            vv = *reinterpret_cast<const float4*>(&gin[ci*1024 + gy*32 + 4*x4]);
        int base = (r*34 + 4*x4 + 1)*24 + ci;
        float fv[4] = {vv.x, vv.y, vv.z, vv.w};
        #pragma unroll
        for (int d = 0; d < 4; ++d) {
            u16 hi = f2bf_rne(fv[d]);
            imgHi[base + d*24] = hi;
            imgLo[base + d*24] = f2bf_rne(fv[d] - bf2f(hi));
        }
    }
    __syncthreads();

    const int wv   = __builtin_amdgcn_readfirstlane(t >> 6);
    const int lane = t & 63;
    const int lg   = lane >> 4;
    const int col  = lane & 15;

    f32x4 acc[2][2][2];
    #pragma unroll
    for (int a0 = 0; a0 < 2; ++a0)
        #pragma unroll
        for (int a1 = 0; a1 < 2; ++a1)
            #pragma unroll
            for (int a2 = 0; a2 < 2; ++a2)
                acc[a0][a1][a2] = (f32x4){0.f,0.f,0.f,0.f};

    const short8v* w2h8 = (const short8v*)w2hi;
    const short8v* w2l8 = (const short8v*)w2lo;

    #pragma unroll
    for (int g = 0; g < 5; ++g) {
        short8v ah[2], al[2];
        #pragma unroll
        for (int ct = 0; ct < 2; ++ct) {
            int fidx = ((g*4 + lg)*2 + ct)*16 + col;
            ah[ct] = w2h8[fidx];
            al[ct] = w2l8[fidx];
        }
        int tap = 2*g + (lg >> 1);
        tap = (tap > 8) ? 8 : tap;
        int ky = (tap*11) >> 5;
        int kx = tap - 3*ky;
        int ci0 = (lg & 1)*8;
        #pragma unroll
        for (int ntoy = 0; ntoy < 2; ++ntoy) {
            #pragma unroll
            for (int oxh = 0; oxh < 2; ++oxh) {
                int addr = ((2*wv + ntoy + ky)*34 + oxh*16 + col + kx)*24 + ci0;
                short8v bh = *(const short8v*)&imgHi[addr];
                short8v bl = *(const short8v*)&imgLo[addr];
                #pragma unroll
                for (int ct = 0; ct < 2; ++ct) {
                    acc[ct][ntoy][oxh] = __builtin_amdgcn_mfma_f32_16x16x32_bf16(
                        ah[ct], bh, acc[ct][ntoy][oxh], 0, 0, 0);
                    acc[ct][ntoy][oxh] = __builtin_amdgcn_mfma_f32_16x16x32_bf16(
                        ah[ct], bl, acc[ct][ntoy][oxh], 0, 0, 0);
                    acc[ct][ntoy][oxh] = __builtin_amdgcn_mfma_f32_16x16x32_bf16(
                        al[ct], bh, acc[ct][ntoy][oxh], 0, 0, 0);
                }
            }
        }
    }

    #pragma unroll
    for (int ct = 0; ct < 2; ++ct) {
        #pragma unroll
        for (int oxh = 0; oxh < 2; ++oxh) {
            #pragma unroll
            for (int r = 0; r < 4; ++r) {
                int co = ct*16 + 4*lg + r;
                float sc = sscale[co], sh = sshift[co];
                float v0 = fmaf(acc[ct][0][oxh][r], sc, sh);
                float v1 = fmaf(acc[ct][1][oxh][r], sc, sh);
                float m = fmaxf(v0, v1);
                float o = __shfl_xor(m, 1);
                m = fmaxf(fmaxf(m, o), 0.f);
                if (!(col & 1)) {
                    int px = oxh*8 + (col >> 1);
                    g2[(((size_t)im*32 + co) << 8) + (8*h + wv)*16 + px] = m;
                }
            }
        }
    }
}

// ------- Stage 3: conv3(32->64) MFMA + BN/ReLU/pool + proj + quantum + cls -------
__global__ __launch_bounds__(512)
void stage3_kernel(const float* __restrict__ g2,
                   const u16* __restrict__ w3hi, const u16* __restrict__ w3lo,
                   const float* __restrict__ cb,
                   const float* __restrict__ bg,
                   const float* __restrict__ bb,
                   const float* __restrict__ bm,
                   const float* __restrict__ bv,
                   const float* __restrict__ pw,
                   const float* __restrict__ pb,
                   const float* __restrict__ cw,
                   const float* __restrict__ cbias,
                   float* __restrict__ out)
{
    __shared__ alignas(16) u16 imgHi[18*18*40];
    __shared__ alignas(16) u16 imgLo[18*18*40];
    __shared__ float sscale[64];
    __shared__ float sshift[64];
    __shared__ float red[8][4];
    float* fbuf = (float*)imgHi;
    const int b = blockIdx.x;
    const int t = threadIdx.x;

    {
        uint32* p0 = (uint32*)imgHi;
        uint32* p1 = (uint32*)imgLo;
        for (int i = t; i < 6480; i += 512) { p0[i] = 0u; p1[i] = 0u; }
    }
    if (t < 64) {
        float inv = bg[t] * rsqrtf(bv[t] + BN_EPS);
        sscale[t] = inv;
        sshift[t] = cb[t]*inv + bb[t] - bm[t]*inv;
    }
    __syncthreads();

    const float* gin = g2 + (size_t)b*8192;
    #pragma unroll
    for (int k = 0; k < 4; ++k) {
        int i4 = t + k*512;
        int x4 = i4 & 3;
        int y  = (i4 >> 2) & 15;
        int ci = i4 >> 6;
        float4 vv = *reinterpret_cast<const float4*>(&gin[ci*256 + y*16 + 4*x4]);
        int base = ((y+1)*18 + 4*x4 + 1)*40 + ci;
        float fv[4] = {vv.x, vv.y, vv.z, vv.w};
        #pragma unroll
        for (int d = 0; d < 4; ++d) {
            u16 hi = f2bf_rne(fv[d]);
            imgHi[base + d*40] = hi;
            imgLo[base + d*40] = f2bf_rne(fv[d] - bf2f(hi));
        }
    }
    __syncthreads();

    const int wv   = __builtin_amdgcn_readfirstlane(t >> 6);
    const int lane = t & 63;
    const int lg   = lane >> 4;
    const int col  = lane & 15;

    f32x4 acc[4][2];
    #pragma unroll
    for (int a0 = 0; a0 < 4; ++a0) {
        acc[a0][0] = (f32x4){0.f,0.f,0.f,0.f};
        acc[a0][1] = (f32x4){0.f,0.f,0.f,0.f};
    }

    const short8v* w3h8 = (const short8v*)w3hi;
    const short8v* w3l8 = (const short8v*)w3lo;

    #pragma unroll
    for (int g = 0; g < 9; ++g) {
        short8v ah[4], al[4];
        #pragma unroll
        for (int ct = 0; ct < 4; ++ct) {
            int fidx = ((g*4 + lg)*4 + ct)*16 + col;
            ah[ct] = w3h8[fidx];
            al[ct] = w3l8[fidx];
        }
        int ky = (g*11) >> 5;
        int kx = g - 3*ky;
        int ci0 = 8*lg;
        #pragma unroll
        for (int ntoy = 0; ntoy < 2; ++ntoy) {
            int addr = ((2*wv + ntoy + ky)*18 + col + kx)*40 + ci0;
            short8v bh = *(const short8v*)&imgHi[addr];
            short8v bl = *(const short8v*)&imgLo[addr];
            #pragma unroll
            for (int ct = 0; ct < 4; ++ct) {
                acc[ct][ntoy] = __builtin_amdgcn_mfma_f32_16x16x32_bf16(
                    ah[ct], bh, acc[ct][ntoy], 0, 0, 0);
                acc[ct][ntoy] = __builtin_amdgcn_mfma_f32_16x16x32_bf16(
                    ah[ct], bl, acc[ct][ntoy], 0, 0, 0);
                acc[ct][ntoy] = __builtin_amdgcn_mfma_f32_16x16x32_bf16(
                    al[ct], bh, acc[ct][ntoy], 0, 0, 0);
            }
        }
    }
    __syncthreads();

    #pragma unroll
    for (int ct = 0; ct < 4; ++ct) {
        #pragma unroll
        for (int r = 0; r < 4; ++r) {
            int co = ct*16 + 4*lg + r;
            float sc = sscale[co], sh = sshift[co];
            float v0 = fmaf(acc[ct][0][r], sc, sh);
            float v1 = fmaf(acc[ct][1][r], sc, sh);
            float m = fmaxf(v0, v1);
            float o = __shfl_xor(m, 1);
            m = fmaxf(fmaxf(m, o), 0.f);
            if (!(col & 1))
                fbuf[co*64 + wv*8 + (col >> 1)] = m;
        }
    }
    __syncthreads();

    float z0=0.f, z1=0.f, z2=0.f, z3=0.f;
    #pragma unroll
    for (int k = 0; k < 8; ++k) {
        int j = k*512 + t;
        float fv = fbuf[j];
        z0 = fmaf(fv, pw[        j], z0);
        z1 = fmaf(fv, pw[ 4096 + j], z1);
        z2 = fmaf(fv, pw[ 8192 + j], z2);
        z3 = fmaf(fv, pw[12288 + j], z3);
    }
    #pragma unroll
    for (int off2 = 32; off2 > 0; off2 >>= 1) {
        z0 += __shfl_down(z0, off2);
        z1 += __shfl_down(z1, off2);
        z2 += __shfl_down(z2, off2);
        z3 += __shfl_down(z3, off2);
    }
    if (lane == 0) { red[wv][0]=z0; red[wv][1]=z1; red[wv][2]=z2; red[wv][3]=z3; }
    __syncthreads();

    if (t == 0) {
        float z[4];
        #pragma unroll
        for (int p2 = 0; p2 < 4; ++p2) {
            float s = pb[p2];
            #pragma unroll
            for (int r = 0; r < 8; ++r) s += red[r][p2];
            z[p2] = s;
        }
        float qc[4], qs[4];
        #pragma unroll
        for (int k = 0; k < 4; ++k) {
            float hh = 0.5f * ALPHA * z[k];
            qc[k] = cosf(hh);
            qs[k] = sinf(hh);
        }
        float st[16];
        #pragma unroll
        for (int j = 0; j < 16; ++j) {
            float v0 = ((j>>3)&1) ? qs[0] : qc[0];
            float v1 = ((j>>2)&1) ? qs[1] : qc[1];
            float v2 = ((j>>1)&1) ? qs[2] : qc[2];
            float v3 = ( j    &1) ? qs[3] : qc[3];
            st[j] = v0*v1*v2*v3;
        }
        const int csrc[4] = {0,1,2,3};
        const int ctgt[4] = {1,2,3,0};
        #pragma unroll
        for (int pp = 0; pp < 4; ++pp) {
            float tmp[16];
            #pragma unroll
            for (int idx = 0; idx < 16; ++idx) {
                int bit = (idx >> (3 - csrc[pp])) & 1;
                int src = bit ? (idx ^ (1 << (3 - ctgt[pp]))) : idx;
                tmp[idx] = st[src];
            }
            #pragma unroll
            for (int idx = 0; idx < 16; ++idx) st[idx] = tmp[idx];
        }
        float feat[10];
        #pragma unroll
        for (int f = 0; f < 10; ++f) feat[f] = 0.f;
        #pragma unroll
        for (int j = 0; j < 16; ++j) {
            float pr = st[j]*st[j];
            float s0 = ((j>>3)&1) ? -1.f : 1.f;
            float s1 = ((j>>2)&1) ? -1.f : 1.f;
            float s2 = ((j>>1)&1) ? -1.f : 1.f;
            float s3 = ( j    &1) ? -1.f : 1.f;
            feat[0] += s0*pr;       feat[1] += s1*pr;
            feat[2] += s2*pr;       feat[3] += s3*pr;
            feat[4] += s0*s1*pr;    feat[5] += s0*s2*pr;
            feat[6] += s0*s3*pr;    feat[7] += s1*s2*pr;
            feat[8] += s1*s3*pr;    feat[9] += s2*s3*pr;
        }
        #pragma unroll
        for (int o = 0; o < 10; ++o) {
            float a = cbias[o];
            #pragma unroll
            for (int f = 0; f < 10; ++f) a = fmaf(feat[f], cw[o*10+f], a);
            out[(size_t)b*10 + o] = a;
        }
    }
}

extern "C" void kernel_launch(void* const* d_in, const int* in_sizes, int n_in,
                              void* d_out, int out_size, void* d_ws, size_t ws_size,
                              hipStream_t stream)
{
    const float* x   = (const float*)d_in[0];
    const float* c1w = (const float*)d_in[1];
    const float* c1b = (const float*)d_in[2];
    const float* c2w = (const float*)d_in[3];
    const float* c2b = (const float*)d_in[4];
    const float* c3w = (const float*)d_in[5];
    const float* c3b = (const float*)d_in[6];
    const float* b1g = (const float*)d_in[7];
    const float* b1b = (const float*)d_in[8];
    const float* b1m = (const float*)d_in[9];
    const float* b1v = (const float*)d_in[10];
    const float* b2g = (const float*)d_in[11];
    const float* b2b = (const float*)d_in[12];
    const float* b2m = (const float*)d_in[13];
    const float* b2v = (const float*)d_in[14];
    const float* b3g = (const float*)d_in[15];
    const float* b3b = (const float*)d_in[16];
    const float* b3m = (const float*)d_in[17];
    const float* b3v = (const float*)d_in[18];
    const float* pw  = (const float*)d_in[19];
    const float* pb  = (const float*)d_in[20];
    const float* cw  = (const float*)d_in[21];
    const float* cbv = (const float*)d_in[22];

    char* wsb = (char*)d_ws;
    float* g1 = (float*)wsb;                               // 64 MB
    float* g2 = (float*)(wsb + 67108864);                  // 32 MB
    u16* w2hi = (u16*)(wsb + 100663296);                   // frag arrays (~92 KB)
    u16* w2lo = w2hi + 5120;
    u16* w3hi = w2lo + 5120;
    u16* w3lo = w3hi + 18432;
    float* out = (float*)d_out;

    prep_kernel  <<<  72, 256, 0, stream>>>(c2w, c3w, w2hi, w2lo, w3hi, w3lo);
    stage1_kernel<<<2048, 512, 0, stream>>>(x,  c1w, c1b, b1g, b1b, b1m, b1v, g1);
    stage2_kernel<<<2048, 512, 0, stream>>>(g1, w2hi, w2lo, c2b, b2g, b2b, b2m, b2v, g2);
    stage3_kernel<<<1024, 512, 0, stream>>>(g2, w3hi, w3lo, c3b, b3g, b3b, b3m, b3v,
                                            pw, pb, cw, cbv, out);
}

// Round 11
// 219.287 us; speedup vs baseline: 1.1552x; 1.0296x over previous
//
#include <hip/hip_runtime.h>
#include <math.h>

#define ALPHA 1.57f
#define BN_EPS 1e-5f

typedef __attribute__((ext_vector_type(8))) short short8v;
typedef __attribute__((ext_vector_type(4))) short short4v;
typedef __attribute__((ext_vector_type(4))) float f32x4;
typedef unsigned int uint32;
typedef unsigned short u16;

__device__ __forceinline__ u16 f2bf_rne(float f) {
    uint32 u = __float_as_uint(f);
    u += 0x7FFFu + ((u >> 16) & 1u);
    return (u16)(u >> 16);
}
__device__ __forceinline__ float bf2f(u16 h) {
    return __uint_as_float(((uint32)h) << 16);
}
// pack two bf16 (lane 2c -> low, 2c+1 -> high)
__device__ __forceinline__ uint32 pack2(u16 a, u16 b) {
    return (uint32)a | ((uint32)b << 16);
}

// ---------------- Prep: split-bf16 weight fragments (once per call) ----------------
__global__ __launch_bounds__(256)
void prep_kernel(const float* __restrict__ w2, const float* __restrict__ w3,
                 u16* __restrict__ w2hi, u16* __restrict__ w2lo,
                 u16* __restrict__ w3hi, u16* __restrict__ w3lo)
{
    int t = blockIdx.x*256 + threadIdx.x;
    if (t < 5120) {
        int j = t & 7, col = (t>>3)&15, ct = (t>>7)&1, lg = (t>>8)&3, g = t>>10;
        int k = 32*g + 8*lg + j;
        int tap = k >> 4, ci = k & 15;
        float v = (tap < 9) ? w2[(ct*16+col)*144 + ci*9 + tap] : 0.f;
        u16 hi = f2bf_rne(v);
        w2hi[t] = hi;
        w2lo[t] = f2bf_rne(v - bf2f(hi));
    }
    if (t < 18432) {
        int j = t & 7, col = (t>>3)&15, ct = (t>>7)&3, lg = (t>>9)&3, g = t>>11;
        int ci = 8*lg + j;                 // tap = g
        float v = w3[(ct*16+col)*288 + ci*9 + g];
        u16 hi = f2bf_rne(v);
        w3hi[t] = hi;
        w3lo[t] = f2bf_rne(v - bf2f(hi));
    }
}

// ---------------- Stage 1: conv1(3->16) via MFMA implicit GEMM ----------------
// x (1024,3,64,64) -> g1 (1024,16,32,32).  2 blocks/image, 512 thr.
// LDS planes u16 [34 rows][66 cols][4 ci]; staging writes packed dwords (ci-pair).
__global__ __launch_bounds__(512)
void stage1_kernel(const float* __restrict__ x,
                   const float* __restrict__ w,    // (16,3,3,3): co*27 + ci*9 + tap
                   const float* __restrict__ cb,
                   const float* __restrict__ bg,
                   const float* __restrict__ bb,
                   const float* __restrict__ bm,
                   const float* __restrict__ bv,
                   float* __restrict__ g1)
{
    __shared__ alignas(16) u16 imgHi[34*66*4];   // 8976 u16
    __shared__ alignas(16) u16 imgLo[34*66*4];
    __shared__ float sscale[16];
    __shared__ float sshift[16];
    const int im = blockIdx.x >> 1;
    const int h  = blockIdx.x & 1;
    const int t  = threadIdx.x;

    {   // zero both planes (pads must be 0)
        uint32* p0 = (uint32*)imgHi;
        uint32* p1 = (uint32*)imgLo;
        for (int i = t; i < 4488; i += 512) { p0[i] = 0u; p1[i] = 0u; }
    }
    if (t < 16) {
        float inv = bg[t] * rsqrtf(bv[t] + BN_EPS);
        sscale[t] = inv;
        sshift[t] = cb[t]*inv + bb[t] - bm[t]*inv;
    }
    __syncthreads();

    // staging: thread owns (ci-pair c, cx4, ry); writes packed dwords, bank-spread
    const float* xin = x + (size_t)im*12288;
    uint32* hi32 = (uint32*)imgHi;
    uint32* lo32 = (uint32*)imgLo;
    for (int i = t; i < 1088; i += 512) {      // 2c * 16cx4 * 34ry
        int c   = i & 1;
        int cx  = ((i >> 1) & 15) * 4;
        int ry  = i >> 5;
        int gy  = 32*h - 1 + ry;
        float4 v0 = make_float4(0.f,0.f,0.f,0.f);
        float4 v1 = make_float4(0.f,0.f,0.f,0.f);
        if (gy >= 0 && gy < 64) {
            v0 = *reinterpret_cast<const float4*>(&xin[(2*c  )*4096 + gy*64 + cx]);
            if (c == 0)
                v1 = *reinterpret_cast<const float4*>(&xin[       4096 + gy*64 + cx]);
        }
        float f0[4] = {v0.x, v0.y, v0.z, v0.w};
        float f1[4] = {v1.x, v1.y, v1.z, v1.w};
        #pragma unroll
        for (int d = 0; d < 4; ++d) {
            u16 h0 = f2bf_rne(f0[d]);
            u16 h1 = f2bf_rne(f1[d]);
            u16 l0 = f2bf_rne(f0[d] - bf2f(h0));
            u16 l1 = f2bf_rne(f1[d] - bf2f(h1));
            int dw = (ry*66 + cx + d + 1)*2 + c;
            hi32[dw] = pack2(h0, h1);
            lo32[dw] = pack2(l0, l1);
        }
    }
    __syncthreads();

    const int wv   = __builtin_amdgcn_readfirstlane(t >> 6);
    const int lane = t & 63;
    const int lg   = lane >> 4;
    const int col  = lane & 15;

    // A fragments from global (L2-hot), built once per block.
    short8v ah0, al0, ah1, al1;
    #pragma unroll
    for (int j = 0; j < 8; ++j) {
        int ci  = j & 3;
        int tap = 2*lg + (j >> 2);
        float v0 = (ci < 3) ? w[col*27 + ci*9 + tap] : 0.f;
        u16 hi = f2bf_rne(v0);
        ah0[j] = (short)hi;
        al0[j] = (short)f2bf_rne(v0 - bf2f(hi));
        int tap1 = 8 + 2*lg + (j >> 2);
        float v1 = (ci < 3 && tap1 < 9) ? w[col*27 + ci*9 + tap1] : 0.f;
        hi = f2bf_rne(v1);
        ah1[j] = (short)hi;
        al1[j] = (short)f2bf_rne(v1 - bf2f(hi));
    }

    const int tA = 2*lg, tB = 2*lg + 1;
    const int offA = ((tA/3)*66 + (tA - 3*(tA/3)))*4;
    const int offB = ((tB/3)*66 + (tB - 3*(tB/3)))*4;
    const int offC = (2*66 + 2)*4;

    for (int q = 0; q < 2; ++q) {
        int py = 2*wv + q;
        #pragma unroll
        for (int ct4 = 0; ct4 < 4; ++ct4) {
            int ox = ct4*16 + col;
            f32x4 acc[2];
            acc[0] = (f32x4){0.f,0.f,0.f,0.f};
            acc[1] = (f32x4){0.f,0.f,0.f,0.f};
            #pragma unroll
            for (int rr = 0; rr < 2; ++rr) {
                int r = 2*py + rr;
                int base = (r*66 + ox)*4;
                short8v bh0, bl0, bh1, bl1;
                *reinterpret_cast<short4v*>(&bh0) =
                    *reinterpret_cast<const short4v*>(&imgHi[base + offA]);
                *(reinterpret_cast<short4v*>(&bh0) + 1) =
                    *reinterpret_cast<const short4v*>(&imgHi[base + offB]);
                *reinterpret_cast<short4v*>(&bl0) =
                    *reinterpret_cast<const short4v*>(&imgLo[base + offA]);
                *(reinterpret_cast<short4v*>(&bl0) + 1) =
                    *reinterpret_cast<const short4v*>(&imgLo[base + offB]);
                *reinterpret_cast<short4v*>(&bh1) =
                    *reinterpret_cast<const short4v*>(&imgHi[base + offC]);
                *(reinterpret_cast<short4v*>(&bh1) + 1) = (short4v){0,0,0,0};
                *reinterpret_cast<short4v*>(&bl1) =
                    *reinterpret_cast<const short4v*>(&imgLo[base + offC]);
                *(reinterpret_cast<short4v*>(&bl1) + 1) = (short4v){0,0,0,0};

                acc[rr] = __builtin_amdgcn_mfma_f32_16x16x32_bf16(ah0, bh0, acc[rr], 0,0,0);
                acc[rr] = __builtin_amdgcn_mfma_f32_16x16x32_bf16(ah0, bl0, acc[rr], 0,0,0);
                acc[rr] = __builtin_amdgcn_mfma_f32_16x16x32_bf16(al0, bh0, acc[rr], 0,0,0);
                acc[rr] = __builtin_amdgcn_mfma_f32_16x16x32_bf16(ah1, bh1, acc[rr], 0,0,0);
                acc[rr] = __builtin_amdgcn_mfma_f32_16x16x32_bf16(ah1, bl1, acc[rr], 0,0,0);
                acc[rr] = __builtin_amdgcn_mfma_f32_16x16x32_bf16(al1, bh1, acc[rr], 0,0,0);
            }
            #pragma unroll
            for (int r2 = 0; r2 < 4; ++r2) {
                int co = 4*lg + r2;
                float sc = sscale[co], sh = sshift[co];
                float v0 = fmaf(acc[0][r2], sc, sh);
                float v1 = fmaf(acc[1][r2], sc, sh);
                float m = fmaxf(v0, v1);
                float o = __shfl_xor(m, 1);
                m = fmaxf(fmaxf(m, o), 0.f);
                if (!(col & 1)) {
                    int px = ox >> 1;
                    g1[(((size_t)im*16 + co) << 10) + (16*h + py)*32 + px] = m;
                }
            }
        }
    }
}

// ---------------- Stage 2: conv2(16->32) MFMA, channel-last hi/lo LDS ----------------
// staging writes packed dwords (ci-pair) -> bank-conflict-free.
__global__ __launch_bounds__(512)
void stage2_kernel(const float* __restrict__ g1,
                   const u16* __restrict__ w2hi, const u16* __restrict__ w2lo,
                   const float* __restrict__ cb,
                   const float* __restrict__ bg,
                   const float* __restrict__ bb,
                   const float* __restrict__ bm,
                   const float* __restrict__ bv,
                   float* __restrict__ g2)
{
    __shared__ alignas(16) u16 imgHi[18*34*24];
    __shared__ alignas(16) u16 imgLo[18*34*24];
    __shared__ float sscale[32];
    __shared__ float sshift[32];
    const int im = blockIdx.x >> 1;
    const int h  = blockIdx.x & 1;
    const int t  = threadIdx.x;

    {
        uint32* p0 = (uint32*)imgHi;
        uint32* p1 = (uint32*)imgLo;
        for (int i = t; i < 7344; i += 512) { p0[i] = 0u; p1[i] = 0u; }
    }
    if (t < 32) {
        float inv = bg[t] * rsqrtf(bv[t] + BN_EPS);
        sscale[t] = inv;
        sshift[t] = cb[t]*inv + bb[t] - bm[t]*inv;
    }
    __syncthreads();

    const float* gin = g1 + (size_t)im*16384;
    uint32* hi32 = (uint32*)imgHi;
    uint32* lo32 = (uint32*)imgLo;
    for (int i = t; i < 1152; i += 512) {      // 8c * 8x4 * 18r
        int c   = i & 7;
        int x4  = (i >> 3) & 7;
        int r   = i >> 6;
        int gy  = 16*h - 1 + r;
        float4 v0 = make_float4(0.f,0.f,0.f,0.f);
        float4 v1 = make_float4(0.f,0.f,0.f,0.f);
        if (gy >= 0 && gy < 32) {
            v0 = *reinterpret_cast<const float4*>(&gin[(2*c  )*1024 + gy*32 + 4*x4]);
            v1 = *reinterpret_cast<const float4*>(&gin[(2*c+1)*1024 + gy*32 + 4*x4]);
        }
        float f0[4] = {v0.x, v0.y, v0.z, v0.w};
        float f1[4] = {v1.x, v1.y, v1.z, v1.w};
        #pragma unroll
        for (int d = 0; d < 4; ++d) {
            u16 h0 = f2bf_rne(f0[d]);
            u16 h1 = f2bf_rne(f1[d]);
            u16 l0 = f2bf_rne(f0[d] - bf2f(h0));
            u16 l1 = f2bf_rne(f1[d] - bf2f(h1));
            int dw = (r*34 + 4*x4 + d + 1)*12 + c;
            hi32[dw] = pack2(h0, h1);
            lo32[dw] = pack2(l0, l1);
        }
    }
    __syncthreads();

    const int wv   = __builtin_amdgcn_readfirstlane(t >> 6);
    const int lane = t & 63;
    const int lg   = lane >> 4;
    const int col  = lane & 15;

    f32x4 acc[2][2][2];
    #pragma unroll
    for (int a0 = 0; a0 < 2; ++a0)
        #pragma unroll
        for (int a1 = 0; a1 < 2; ++a1)
            #pragma unroll
            for (int a2 = 0; a2 < 2; ++a2)
                acc[a0][a1][a2] = (f32x4){0.f,0.f,0.f,0.f};

    const short8v* w2h8 = (const short8v*)w2hi;
    const short8v* w2l8 = (const short8v*)w2lo;

    #pragma unroll
    for (int g = 0; g < 5; ++g) {
        short8v ah[2], al[2];
        #pragma unroll
        for (int ct = 0; ct < 2; ++ct) {
            int fidx = ((g*4 + lg)*2 + ct)*16 + col;
            ah[ct] = w2h8[fidx];
            al[ct] = w2l8[fidx];
        }
        int tap = 2*g + (lg >> 1);
        tap = (tap > 8) ? 8 : tap;
        int ky = (tap*11) >> 5;
        int kx = tap - 3*ky;
        int ci0 = (lg & 1)*8;
        #pragma unroll
        for (int ntoy = 0; ntoy < 2; ++ntoy) {
            #pragma unroll
            for (int oxh = 0; oxh < 2; ++oxh) {
                int addr = ((2*wv + ntoy + ky)*34 + oxh*16 + col + kx)*24 + ci0;
                short8v bh = *(const short8v*)&imgHi[addr];
                short8v bl = *(const short8v*)&imgLo[addr];
                #pragma unroll
                for (int ct = 0; ct < 2; ++ct) {
                    acc[ct][ntoy][oxh] = __builtin_amdgcn_mfma_f32_16x16x32_bf16(
                        ah[ct], bh, acc[ct][ntoy][oxh], 0, 0, 0);
                    acc[ct][ntoy][oxh] = __builtin_amdgcn_mfma_f32_16x16x32_bf16(
                        ah[ct], bl, acc[ct][ntoy][oxh], 0, 0, 0);
                    acc[ct][ntoy][oxh] = __builtin_amdgcn_mfma_f32_16x16x32_bf16(
                        al[ct], bh, acc[ct][ntoy][oxh], 0, 0, 0);
                }
            }
        }
    }

    #pragma unroll
    for (int ct = 0; ct < 2; ++ct) {
        #pragma unroll
        for (int oxh = 0; oxh < 2; ++oxh) {
            #pragma unroll
            for (int r = 0; r < 4; ++r) {
                int co = ct*16 + 4*lg + r;
                float sc = sscale[co], sh = sshift[co];
                float v0 = fmaf(acc[ct][0][oxh][r], sc, sh);
                float v1 = fmaf(acc[ct][1][oxh][r], sc, sh);
                float m = fmaxf(v0, v1);
                float o = __shfl_xor(m, 1);
                m = fmaxf(fmaxf(m, o), 0.f);
                if (!(col & 1)) {
                    int px = oxh*8 + (col >> 1);
                    g2[(((size_t)im*32 + co) << 8) + (8*h + wv)*16 + px] = m;
                }
            }
        }
    }
}

// ------- Stage 3: conv3(32->64) MFMA + BN/ReLU/pool + proj + quantum + cls -------
// staging writes packed dwords (ci-pair) -> bank-conflict-free.
__global__ __launch_bounds__(512)
void stage3_kernel(const float* __restrict__ g2,
                   const u16* __restrict__ w3hi, const u16* __restrict__ w3lo,
                   const float* __restrict__ cb,
                   const float* __restrict__ bg,
                   const float* __restrict__ bb,
                   const float* __restrict__ bm,
                   const float* __restrict__ bv,
                   const float* __restrict__ pw,
                   const float* __restrict__ pb,
                   const float* __restrict__ cw,
                   const float* __restrict__ cbias,
                   float* __restrict__ out)
{
    __shared__ alignas(16) u16 imgHi[18*18*40];
    __shared__ alignas(16) u16 imgLo[18*18*40];
    __shared__ float sscale[64];
    __shared__ float sshift[64];
    __shared__ float red[8][4];
    float* fbuf = (float*)imgHi;
    const int b = blockIdx.x;
    const int t = threadIdx.x;

    {
        uint32* p0 = (uint32*)imgHi;
        uint32* p1 = (uint32*)imgLo;
        for (int i = t; i < 6480; i += 512) { p0[i] = 0u; p1[i] = 0u; }
    }
    if (t < 64) {
        float inv = bg[t] * rsqrtf(bv[t] + BN_EPS);
        sscale[t] = inv;
        sshift[t] = cb[t]*inv + bb[t] - bm[t]*inv;
    }
    __syncthreads();

    const float* gin = g2 + (size_t)b*8192;
    uint32* hi32 = (uint32*)imgHi;
    uint32* lo32 = (uint32*)imgLo;
    #pragma unroll
    for (int kk = 0; kk < 2; ++kk) {
        int i  = t + kk*512;                   // 16c * 4x4 * 16y = 1024
        int c  = i & 15;
        int x4 = (i >> 4) & 3;
        int y  = i >> 6;
        float4 v0 = *reinterpret_cast<const float4*>(&gin[(2*c  )*256 + y*16 + 4*x4]);
        float4 v1 = *reinterpret_cast<const float4*>(&gin[(2*c+1)*256 + y*16 + 4*x4]);
        float f0[4] = {v0.x, v0.y, v0.z, v0.w};
        float f1[4] = {v1.x, v1.y, v1.z, v1.w};
        #pragma unroll
        for (int d = 0; d < 4; ++d) {
            u16 h0 = f2bf_rne(f0[d]);
            u16 h1 = f2bf_rne(f1[d]);
            u16 l0 = f2bf_rne(f0[d] - bf2f(h0));
            u16 l1 = f2bf_rne(f1[d] - bf2f(h1));
            int dw = ((y+1)*18 + 4*x4 + d + 1)*20 + c;
            hi32[dw] = pack2(h0, h1);
            lo32[dw] = pack2(l0, l1);
        }
    }
    __syncthreads();

    const int wv   = __builtin_amdgcn_readfirstlane(t >> 6);
    const int lane = t & 63;
    const int lg   = lane >> 4;
    const int col  = lane & 15;

    f32x4 acc[4][2];
    #pragma unroll
    for (int a0 = 0; a0 < 4; ++a0) {
        acc[a0][0] = (f32x4){0.f,0.f,0.f,0.f};
        acc[a0][1] = (f32x4){0.f,0.f,0.f,0.f};
    }

    const short8v* w3h8 = (const short8v*)w3hi;
    const short8v* w3l8 = (const short8v*)w3lo;

    #pragma unroll
    for (int g = 0; g < 9; ++g) {
        short8v ah[4], al[4];
        #pragma unroll
        for (int ct = 0; ct < 4; ++ct) {
            int fidx = ((g*4 + lg)*4 + ct)*16 + col;
            ah[ct] = w3h8[fidx];
            al[ct] = w3l8[fidx];
        }
        int ky = (g*11) >> 5;
        int kx = g - 3*ky;
        int ci0 = 8*lg;
        #pragma unroll
        for (int ntoy = 0; ntoy < 2; ++ntoy) {
            int addr = ((2*wv + ntoy + ky)*18 + col + kx)*40 + ci0;
            short8v bh = *(const short8v*)&imgHi[addr];
            short8v bl = *(const short8v*)&imgLo[addr];
            #pragma unroll
            for (int ct = 0; ct < 4; ++ct) {
                acc[ct][ntoy] = __builtin_amdgcn_mfma_f32_16x16x32_bf16(
                    ah[ct], bh, acc[ct][ntoy], 0, 0, 0);
                acc[ct][ntoy] = __builtin_amdgcn_mfma_f32_16x16x32_bf16(
                    ah[ct], bl, acc[ct][ntoy], 0, 0, 0);
                acc[ct][ntoy] = __builtin_amdgcn_mfma_f32_16x16x32_bf16(
                    al[ct], bh, acc[ct][ntoy], 0, 0, 0);
            }
        }
    }
    __syncthreads();

    #pragma unroll
    for (int ct = 0; ct < 4; ++ct) {
        #pragma unroll
        for (int r = 0; r < 4; ++r) {
            int co = ct*16 + 4*lg + r;
            float sc = sscale[co], sh = sshift[co];
            float v0 = fmaf(acc[ct][0][r], sc, sh);
            float v1 = fmaf(acc[ct][1][r], sc, sh);
            float m = fmaxf(v0, v1);
            float o = __shfl_xor(m, 1);
            m = fmaxf(fmaxf(m, o), 0.f);
            if (!(col & 1))
                fbuf[co*64 + wv*8 + (col >> 1)] = m;
        }
    }
    __syncthreads();

    float z0=0.f, z1=0.f, z2=0.f, z3=0.f;
    #pragma unroll
    for (int k = 0; k < 8; ++k) {
        int j = k*512 + t;
        float fv = fbuf[j];
        z0 = fmaf(fv, pw[        j], z0);
        z1 = fmaf(fv, pw[ 4096 + j], z1);
        z2 = fmaf(fv, pw[ 8192 + j], z2);
        z3 = fmaf(fv, pw[12288 + j], z3);
    }
    #pragma unroll
    for (int off2 = 32; off2 > 0; off2 >>= 1) {
        z0 += __shfl_down(z0, off2);
        z1 += __shfl_down(z1, off2);
        z2 += __shfl_down(z2, off2);
        z3 += __shfl_down(z3, off2);
    }
    if (lane == 0) { red[wv][0]=z0; red[wv][1]=z1; red[wv][2]=z2; red[wv][3]=z3; }
    __syncthreads();

    if (t == 0) {
        float z[4];
        #pragma unroll
        for (int p2 = 0; p2 < 4; ++p2) {
            float s = pb[p2];
            #pragma unroll
            for (int r = 0; r < 8; ++r) s += red[r][p2];
            z[p2] = s;
        }
        float qc[4], qs[4];
        #pragma unroll
        for (int k = 0; k < 4; ++k) {
            float hh = 0.5f * ALPHA * z[k];
            qc[k] = cosf(hh);
            qs[k] = sinf(hh);
        }
        float st[16];
        #pragma unroll
        for (int j = 0; j < 16; ++j) {
            float v0 = ((j>>3)&1) ? qs[0] : qc[0];
            float v1 = ((j>>2)&1) ? qs[1] : qc[1];
            float v2 = ((j>>1)&1) ? qs[2] : qc[2];
            float v3 = ( j    &1) ? qs[3] : qc[3];
            st[j] = v0*v1*v2*v3;
        }
        const int csrc[4] = {0,1,2,3};
        const int ctgt[4] = {1,2,3,0};
        #pragma unroll
        for (int pp = 0; pp < 4; ++pp) {
            float tmp[16];
            #pragma unroll
            for (int idx = 0; idx < 16; ++idx) {
                int bit = (idx >> (3 - csrc[pp])) & 1;
                int src = bit ? (idx ^ (1 << (3 - ctgt[pp]))) : idx;
                tmp[idx] = st[src];
            }
            #pragma unroll
            for (int idx = 0; idx < 16; ++idx) st[idx] = tmp[idx];
        }
        float feat[10];
        #pragma unroll
        for (int f = 0; f < 10; ++f) feat[f] = 0.f;
        #pragma unroll
        for (int j = 0; j < 16; ++j) {
            float pr = st[j]*st[j];
            float s0 = ((j>>3)&1) ? -1.f : 1.f;
            float s1 = ((j>>2)&1) ? -1.f : 1.f;
            float s2 = ((j>>1)&1) ? -1.f : 1.f;
            float s3 = ( j    &1) ? -1.f : 1.f;
            feat[0] += s0*pr;       feat[1] += s1*pr;
            feat[2] += s2*pr;       feat[3] += s3*pr;
            feat[4] += s0*s1*pr;    feat[5] += s0*s2*pr;
            feat[6] += s0*s3*pr;    feat[7] += s1*s2*pr;
            feat[8] += s1*s3*pr;    feat[9] += s2*s3*pr;
        }
        #pragma unroll
        for (int o = 0; o < 10; ++o) {
            float a = cbias[o];
            #pragma unroll
            for (int f = 0; f < 10; ++f) a = fmaf(feat[f], cw[o*10+f], a);
            out[(size_t)b*10 + o] = a;
        }
    }
}

extern "C" void kernel_launch(void* const* d_in, const int* in_sizes, int n_in,
                              void* d_out, int out_size, void* d_ws, size_t ws_size,
                              hipStream_t stream)
{
    const float* x   = (const float*)d_in[0];
    const float* c1w = (const float*)d_in[1];
    const float* c1b = (const float*)d_in[2];
    const float* c2w = (const float*)d_in[3];
    const float* c2b = (const float*)d_in[4];
    const float* c3w = (const float*)d_in[5];
    const float* c3b = (const float*)d_in[6];
    const float* b1g = (const float*)d_in[7];
    const float* b1b = (const float*)d_in[8];
    const float* b1m = (const float*)d_in[9];
    const float* b1v = (const float*)d_in[10];
    const float* b2g = (const float*)d_in[11];
    const float* b2b = (const float*)d_in[12];
    const float* b2m = (const float*)d_in[13];
    const float* b2v = (const float*)d_in[14];
    const float* b3g = (const float*)d_in[15];
    const float* b3b = (const float*)d_in[16];
    const float* b3m = (const float*)d_in[17];
    const float* b3v = (const float*)d_in[18];
    const float* pw  = (const float*)d_in[19];
    const float* pb  = (const float*)d_in[20];
    const float* cw  = (const float*)d_in[21];
    const float* cbv = (const float*)d_in[22];

    char* wsb = (char*)d_ws;
    float* g1 = (float*)wsb;                               // 64 MB
    float* g2 = (float*)(wsb + 67108864);                  // 32 MB
    u16* w2hi = (u16*)(wsb + 100663296);                   // frag arrays (~92 KB)
    u16* w2lo = w2hi + 5120;
    u16* w3hi = w2lo + 5120;
    u16* w3lo = w3hi + 18432;
    float* out = (float*)d_out;

    prep_kernel  <<<  72, 256, 0, stream>>>(c2w, c3w, w2hi, w2lo, w3hi, w3lo);
    stage1_kernel<<<2048, 512, 0, stream>>>(x,  c1w, c1b, b1g, b1b, b1m, b1v, g1);
    stage2_kernel<<<2048, 512, 0, stream>>>(g1, w2hi, w2lo, c2b, b2g, b2b, b2m, b2v, g2);
    stage3_kernel<<<1024, 512, 0, stream>>>(g2, w3hi, w3lo, c3b, b3g, b3b, b3m, b3v,
                                            pw, pb, cw, cbv, out);
}